// Round 16
// baseline (411.453 us; speedup 1.0000x reference)
//
#include <hip/hip_runtime.h>
#include <math.h>

// Problem constants (B=2, S=2048, D=1024, H=16, HD=64, FF=4096)
#define DD   1024
#define HH   16
#define HDD  64
#define FFF  4096
#define NB   2
#define NS   2048
#define NR   (NB * NS)     // 4096 rows
#define TDQ  (3 * DD)      // 3072
#define NKT  (NS / 64)     // 32 KV tiles
#define NSP  2             // KV splits

typedef __attribute__((ext_vector_type(8))) _Float16 hfrag;      // 8 fp16 (MFMA A/B operand)
typedef __attribute__((ext_vector_type(4))) _Float16 h4v;        // 8B pack
typedef __attribute__((ext_vector_type(16))) float f32x16;       // MFMA 32x32 C/D
typedef __attribute__((ext_vector_type(8))) unsigned short us8;  // 16B chunk
typedef __attribute__((ext_vector_type(4))) unsigned int u32x4;

__device__ __forceinline__ float4 ld4(const float* p) {
    return *reinterpret_cast<const float4*>(p);
}
__device__ __forceinline__ float gelu_f(float x) {
    return 0.5f * x * (1.0f + erff(x * 0.70710678118654752440f));
}
// bijective chunked XCD swizzle (m204): consecutive flat ids -> same XCD chunk
__device__ __forceinline__ int xcd_swz(int bid, int nwg) {
    int q = nwg >> 3, r = nwg & 7;
    int xcd = bid & 7, idx = bid >> 3;
    return (xcd < r ? xcd * (q + 1) : r * (q + 1) + (xcd - r) * q) + idx;
}
#define MFMA32H(a, b, c) __builtin_amdgcn_mfma_f32_32x32x16_f16((a), (b), (c), 0, 0, 0)

// ---------------- LayerNorm: fp32 out + fp16 plane
__global__ __launch_bounds__(256) void ln_kernel(const float* __restrict__ in,
        const float* __restrict__ gw, const float* __restrict__ bw,
        float* __restrict__ outf, _Float16* __restrict__ oh) {
    int row = blockIdx.x;
    float4 v = reinterpret_cast<const float4*>(in + (size_t)row * DD)[threadIdx.x];
    float s1 = v.x + v.y + v.z + v.w;
    float s2 = v.x * v.x + v.y * v.y + v.z * v.z + v.w * v.w;
#pragma unroll
    for (int off = 1; off < 64; off <<= 1) {
        s1 += __shfl_xor(s1, off);
        s2 += __shfl_xor(s2, off);
    }
    __shared__ float r1[4], r2[4];
    int wid = threadIdx.x >> 6;
    if ((threadIdx.x & 63) == 0) { r1[wid] = s1; r2[wid] = s2; }
    __syncthreads();
    s1 = r1[0] + r1[1] + r1[2] + r1[3];
    s2 = r2[0] + r2[1] + r2[2] + r2[3];
    float mu   = s1 * (1.0f / DD);
    float var  = s2 * (1.0f / DD) - mu * mu;
    float rstd = rsqrtf(var + 1e-5f);
    float4 g = reinterpret_cast<const float4*>(gw)[threadIdx.x];
    float4 b = reinterpret_cast<const float4*>(bw)[threadIdx.x];
    float o[4];
    o[0] = (v.x - mu) * rstd * g.x + b.x;
    o[1] = (v.y - mu) * rstd * g.y + b.y;
    o[2] = (v.z - mu) * rstd * g.z + b.z;
    o[3] = (v.w - mu) * rstd * g.w + b.w;
    float4 of; of.x = o[0]; of.y = o[1]; of.z = o[2]; of.w = o[3];
    reinterpret_cast<float4*>(outf + (size_t)row * DD)[threadIdx.x] = of;
    h4v hv;
#pragma unroll
    for (int j = 0; j < 4; ++j) hv[j] = (_Float16)o[j];
    *reinterpret_cast<h4v*>(oh + (size_t)row * DD + threadIdx.x * 4) = hv;
}

// ---------------- Weight transpose: W[K][N] fp32 -> T[N][K] fp16
__global__ __launch_bounds__(256) void wt_convert(const float* __restrict__ W,
        _Float16* __restrict__ Th, int K, int N) {
    __shared__ float s[32][33];
    int tx = threadIdx.x & 31, ty = threadIdx.x >> 5;
    int n0 = blockIdx.x * 32, k0 = blockIdx.y * 32;
#pragma unroll
    for (int i = 0; i < 4; ++i)
        s[ty + i * 8][tx] = W[(size_t)(k0 + ty + i * 8) * N + n0 + tx];
    __syncthreads();
#pragma unroll
    for (int i = 0; i < 4; ++i) {
        int n = n0 + ty + i * 8;
        Th[(size_t)n * K + k0 + tx] = (_Float16)s[tx][ty + i * 8];
    }
}

// ---------------- packed cos/sin table
__global__ __launch_bounds__(256) void cs4_table(const float* __restrict__ sp,
        h4v* __restrict__ cs4) {
    int i = blockIdx.x * 256 + threadIdx.x;   // NS*32 total
    int s = i >> 5, d = i & 31;
    float a = sp[s * 64 + d], b = sp[s * 64 + d + 32];
    h4v v;
    v[0] = (_Float16)cosf(a); v[1] = (_Float16)sinf(a);
    v[2] = (_Float16)cosf(b); v[3] = (_Float16)sinf(b);
    cs4[i] = v;
}

// ---------------- mask int32 -> byte
__global__ __launch_bounds__(256) void mask8(const int* __restrict__ mask,
        unsigned char* __restrict__ mb) {
    int i = blockIdx.x * 256 + threadIdx.x;
    int4 v = reinterpret_cast<const int4*>(mask)[i];
    unsigned int o = (unsigned int)(v.x & 1) | ((unsigned int)(v.y & 1) << 8)
                   | ((unsigned int)(v.z & 1) << 16) | ((unsigned int)(v.w & 1) << 24);
    reinterpret_cast<unsigned int*>(mb)[i] = o;
}

// ---------------- V-only transpose: Vr [bh][s][64] -> Vt [bh][d][NS]
__global__ __launch_bounds__(256) void vtrans(const _Float16* __restrict__ Vr,
        _Float16* __restrict__ Vt) {
    __shared__ _Float16 sv[64][72];
    const int t = threadIdx.x;
    const int tile = blockIdx.x, bh = blockIdx.y;
    const int r = t >> 2, p = t & 3;
    const _Float16* src = Vr + ((size_t)bh * NS + tile * 64 + r) * HDD;
    hfrag v0 = *reinterpret_cast<const hfrag*>(src + p * 16);
    hfrag v1 = *reinterpret_cast<const hfrag*>(src + p * 16 + 8);
#pragma unroll
    for (int j = 0; j < 8; ++j) {
        sv[p * 16 + j][r]     = v0[j];
        sv[p * 16 + 8 + j][r] = v1[j];
    }
    __syncthreads();
    {
        int d = t >> 2, kb = (t & 3) * 16;
        size_t obase = ((size_t)bh * HDD + d) * NS + tile * 64 + kb;
        *reinterpret_cast<hfrag*>(Vt + obase)     = *reinterpret_cast<hfrag*>(&sv[d][kb]);
        *reinterpret_cast<hfrag*>(Vt + obase + 8) = *reinterpret_cast<hfrag*>(&sv[d][kb + 8]);
    }
}

// ---------------- Flash attention, batch-paired (round-14 proven, frozen)
__global__ __launch_bounds__(256) void attn_mfma(
        const _Float16* __restrict__ Qp, const _Float16* __restrict__ Kp,
        const _Float16* __restrict__ Vt,
        const float* __restrict__ pos_bias, const unsigned char* __restrict__ maskb,
        float* __restrict__ Opart, float2* __restrict__ Lpart) {
    __shared__ _Float16 kT[2][64][72];    // [batch][kv][d], swizzled
    __shared__ _Float16 vT[2][64][72];    // [batch][d][kv], swizzled
    __shared__ _Float16 PBs[4][32][68];   // per-wave masked bias (shared by batches)
    const int t = threadIdx.x;
    const int w = t >> 6, lane = t & 63, lq = lane & 31, hi = lane >> 5;
    const int h = blockIdx.y;
    const int qt = blockIdx.x, sp = blockIdx.z;
    const int q0 = qt * 128;
    const int qg = q0 + 32 * w + lq;
    const int sw = ((lq >> 3) & 3) << 3;
    const int KT0 = sp * (NKT / NSP), KT1 = KT0 + (NKT / NSP);
    const float C1  = 0.18033688011112042f;   // 0.125 * log2(e)
    const float THR = 11.5f;

    hfrag qf[2][4];
#pragma unroll
    for (int bt = 0; bt < 2; ++bt)
#pragma unroll
        for (int dk = 0; dk < 4; ++dk)
            qf[bt][dk] = *reinterpret_cast<const hfrag*>(
                Qp + ((size_t)(bt * HH + h) * NS + qg) * HDD + 16 * dk + 8 * hi);

    f32x16 o[2][2];
#pragma unroll
    for (int bt = 0; bt < 2; ++bt) { o[bt][0] = (f32x16)0.0f; o[bt][1] = (f32x16)0.0f; }
    float mrun[2] = { -INFINITY, -INFINITY }, lsum[2] = { 0.0f, 0.0f };

    const int sr0 = t >> 2, sc = t & 3;
    const int swr = ((sr0 >> 3) & 3) << 3;
    const int brow = lane >> 4;
    const int bcol = (lane & 15) * 4;
    us8 kr[2][2], vr[2][2];
    float4 pbr[8]; unsigned int pmk[8];

#define STAGE_LOAD(KT) {                                                        \
        int kv0_ = (KT) * 64;                                                   \
        _Pragma("unroll")                                                       \
        for (int bt = 0; bt < 2; ++bt) {                                        \
            size_t kb_ = ((size_t)(bt * HH + h) * NS + kv0_ + sr0) * HDD + 16 * sc; \
            size_t vb_ = ((size_t)(bt * HH + h) * HDD + sr0) * NS + kv0_ + 16 * sc; \
            kr[bt][0] = *reinterpret_cast<const us8*>(Kp + kb_);                \
            kr[bt][1] = *reinterpret_cast<const us8*>(Kp + kb_ + 8);            \
            vr[bt][0] = *reinterpret_cast<const us8*>(Vt + vb_);                \
            vr[bt][1] = *reinterpret_cast<const us8*>(Vt + vb_ + 8);            \
        }                                                                       \
        _Pragma("unroll")                                                       \
        for (int i = 0; i < 8; ++i) {                                           \
            int rg_ = q0 + 32 * w + brow + 4 * i;                               \
            pbr[i] = ld4(pos_bias + ((size_t)h * NS + rg_) * NS + kv0_ + bcol); \
            pmk[i] = *reinterpret_cast<const unsigned int*>(                    \
                         maskb + (size_t)rg_ * NS + kv0_ + bcol);               \
        }                                                                       \
    }

    STAGE_LOAD(KT0);
    for (int kt = KT0; kt < KT1; ++kt) {
        __syncthreads();
#pragma unroll
        for (int bt = 0; bt < 2; ++bt) {
            *reinterpret_cast<us8*>(&kT[bt][sr0][(16 * sc) ^ swr])     = kr[bt][0];
            *reinterpret_cast<us8*>(&kT[bt][sr0][(16 * sc + 8) ^ swr]) = kr[bt][1];
            *reinterpret_cast<us8*>(&vT[bt][sr0][(16 * sc) ^ swr])     = vr[bt][0];
            *reinterpret_cast<us8*>(&vT[bt][sr0][(16 * sc + 8) ^ swr]) = vr[bt][1];
        }
#pragma unroll
        for (int i = 0; i < 8; ++i) {
            h4v pv;
#pragma unroll
            for (int j = 0; j < 4; ++j)
                pv[j] = ((pmk[i] >> (8 * j)) & 0xffu)
                      ? (_Float16)(pbr[i][j] * C1) : (_Float16)(-60000.0f);
            *reinterpret_cast<h4v*>(&PBs[w][brow + 4 * i][bcol]) = pv;
        }
        __syncthreads();
        if (kt + 1 < KT1) STAGE_LOAD(kt + 1);

#pragma unroll
        for (int bt = 0; bt < 2; ++bt) {
            f32x16 s0 = (f32x16)0.0f, s1 = (f32x16)0.0f;
#pragma unroll
            for (int dk = 0; dk < 4; ++dk) {
                hfrag k0 = *reinterpret_cast<const hfrag*>(
                    &kT[bt][lq][(16 * dk + 8 * hi) ^ sw]);
                hfrag k1 = *reinterpret_cast<const hfrag*>(
                    &kT[bt][32 + lq][(16 * dk + 8 * hi) ^ sw]);
                s0 = MFMA32H(k0, qf[bt][dk], s0);
                s1 = MFMA32H(k1, qf[bt][dk], s1);
            }
            float sv[2][16];
#pragma unroll
            for (int m2 = 0; m2 < 2; ++m2)
#pragma unroll
                for (int g = 0; g < 4; ++g) {
                    h4v pb4 = *reinterpret_cast<const h4v*>(
                        &PBs[w][lq][32 * m2 + 8 * g + 4 * hi]);
#pragma unroll
                    for (int j = 0; j < 4; ++j) {
                        int r = 4 * g + j;
                        float sraw = (m2 == 0) ? s0[r] : s1[r];
                        sv[m2][r] = fmaf(sraw, C1, (float)pb4[j]);
                    }
                }
            float mx = sv[0][0];
#pragma unroll
            for (int m2 = 0; m2 < 2; ++m2)
#pragma unroll
                for (int r = 0; r < 16; ++r) mx = fmaxf(mx, sv[m2][r]);
            mx = fmaxf(mx, __shfl_xor(mx, 32));
            if (__any(mx > mrun[bt] + THR)) {
                float mnew = fmaxf(mrun[bt], mx);
                float corr = __builtin_amdgcn_exp2f(mrun[bt] - mnew);
                lsum[bt] *= corr;
                mrun[bt] = mnew;
#pragma unroll
                for (int r = 0; r < 16; ++r) {
                    int iq = (r & 3) + 8 * (r >> 2) + 4 * hi;
                    float cr = __shfl(corr, iq);
                    o[bt][0][r] *= cr; o[bt][1][r] *= cr;
                }
            }
            float ps = 0.0f;
            hfrag af[4];
#pragma unroll
            for (int m2 = 0; m2 < 2; ++m2)
#pragma unroll
                for (int gp = 0; gp < 2; ++gp) {
                    float p0 = __builtin_amdgcn_exp2f(sv[m2][8 * gp + 0] - mrun[bt]);
                    float p1 = __builtin_amdgcn_exp2f(sv[m2][8 * gp + 1] - mrun[bt]);
                    float p2 = __builtin_amdgcn_exp2f(sv[m2][8 * gp + 2] - mrun[bt]);
                    float p3 = __builtin_amdgcn_exp2f(sv[m2][8 * gp + 3] - mrun[bt]);
                    float p4 = __builtin_amdgcn_exp2f(sv[m2][8 * gp + 4] - mrun[bt]);
                    float p5 = __builtin_amdgcn_exp2f(sv[m2][8 * gp + 5] - mrun[bt]);
                    float p6 = __builtin_amdgcn_exp2f(sv[m2][8 * gp + 6] - mrun[bt]);
                    float p7 = __builtin_amdgcn_exp2f(sv[m2][8 * gp + 7] - mrun[bt]);
                    ps += (p0 + p1) + (p2 + p3) + (p4 + p5) + (p6 + p7);
                    unsigned int XA = __builtin_bit_cast(unsigned int, __builtin_amdgcn_cvt_pkrtz(p0, p1));
                    unsigned int XB = __builtin_bit_cast(unsigned int, __builtin_amdgcn_cvt_pkrtz(p2, p3));
                    unsigned int XC = __builtin_bit_cast(unsigned int, __builtin_amdgcn_cvt_pkrtz(p4, p5));
                    unsigned int XD = __builtin_bit_cast(unsigned int, __builtin_amdgcn_cvt_pkrtz(p6, p7));
                    unsigned int YA = (unsigned int)__shfl_xor((int)XA, 32);
                    unsigned int YB = (unsigned int)__shfl_xor((int)XB, 32);
                    unsigned int YC = (unsigned int)__shfl_xor((int)XC, 32);
                    unsigned int YD = (unsigned int)__shfl_xor((int)XD, 32);
                    u32x4 aw;
                    aw[0] = hi ? YC : XA;
                    aw[1] = hi ? YD : XB;
                    aw[2] = hi ? XC : YA;
                    aw[3] = hi ? XD : YB;
                    af[m2 * 2 + gp] = __builtin_bit_cast(hfrag, aw);
                }
            ps += __shfl_xor(ps, 32);
            lsum[bt] += ps;
#pragma unroll
            for (int kp = 0; kp < 4; ++kp) {
                hfrag v0 = *reinterpret_cast<const hfrag*>(
                    &vT[bt][lq][(16 * kp + 8 * hi) ^ sw]);
                hfrag v1 = *reinterpret_cast<const hfrag*>(
                    &vT[bt][32 + lq][(16 * kp + 8 * hi) ^ sw]);
                o[bt][0] = MFMA32H(af[kp], v0, o[bt][0]);
                o[bt][1] = MFMA32H(af[kp], v1, o[bt][1]);
            }
        }
    }
#undef STAGE_LOAD
#pragma unroll
    for (int bt = 0; bt < 2; ++bt) {
        size_t obase = (((size_t)((bt * HH + h) * 16 + qt)) * NSP + sp) * (size_t)(128 * 64);
#pragma unroll
        for (int r = 0; r < 16; ++r) {
            int iq = (r & 3) + 8 * (r >> 2) + 4 * hi;
            Opart[obase + (size_t)(32 * w + iq) * 64 + lq]      = o[bt][0][r];
            Opart[obase + (size_t)(32 * w + iq) * 64 + 32 + lq] = o[bt][1][r];
        }
        if (hi == 0) {
            float2 ml; ml.x = mrun[bt]; ml.y = lsum[bt];
            Lpart[(((size_t)((bt * HH + h) * 16 + qt)) * NSP + sp) * 128 + 32 * w + lq] = ml;
        }
    }
}

// ---------------- combine the two KV-split partials -> fp16 vals
__global__ __launch_bounds__(256) void attn_combine(const float* __restrict__ Opart,
        const float2* __restrict__ Lpart, _Float16* __restrict__ valf) {
    const int qt = blockIdx.x;
    const int h = blockIdx.y >> 1, b = blockIdx.y & 1;
    const int bh = b * HH + h;
    const int t = threadIdx.x;
    const int qloc = t >> 2, d0 = (t & 3) * 16;
    size_t base = ((size_t)(bh * 16 + qt)) * NSP;
#pragma unroll
    for (int half = 0; half < 2; ++half) {
        int q = qloc + 64 * half;
        float2 ml0 = Lpart[(base + 0) * 128 + q];
        float2 ml1 = Lpart[(base + 1) * 128 + q];
        float m = fmaxf(ml0.x, ml1.x);
        float a0 = __builtin_amdgcn_exp2f(ml0.x - m);
        float a1 = __builtin_amdgcn_exp2f(ml1.x - m);
        float inv = 1.0f / (ml0.y * a0 + ml1.y * a1);
        const float* O0 = Opart + (base + 0) * 8192 + (size_t)q * 64 + d0;
        const float* O1 = Opart + (base + 1) * 8192 + (size_t)q * 64 + d0;
        _Float16* dst = valf + ((size_t)(b * NS + qt * 128 + q)) * DD + h * HDD + d0;
#pragma unroll
        for (int j = 0; j < 4; ++j) {
            float4 x0 = ld4(O0 + 4 * j), x1 = ld4(O1 + 4 * j);
            h4v o;
            o[0] = (_Float16)((x0.x * a0 + x1.x * a1) * inv);
            o[1] = (_Float16)((x0.y * a0 + x1.y * a1) * inv);
            o[2] = (_Float16)((x0.z * a0 + x1.z * a1) * inv);
            o[3] = (_Float16)((x0.w * a0 + x1.w * a1) * inv);
            *reinterpret_cast<h4v*>(dst + 4 * j) = o;
        }
    }
}

// ---------------- fp16 MFMA GEMM, 128x128 tile, swizzled LDS, XCD-chunked grid.
// EPI: 1 +bias+resid fp32 ; 2 gelu(+bias) fp16 ; 4 QKV fused-RoPE epilogue.
template<int EPI>
__global__ __launch_bounds__(256, 2) void gemm_h(
        const _Float16* __restrict__ A, const _Float16* __restrict__ B,
        const float* __restrict__ bias, const float* __restrict__ resid,
        float* __restrict__ Cf, _Float16* __restrict__ Ch,
        _Float16* __restrict__ Qp, _Float16* __restrict__ Kp,
        _Float16* __restrict__ Vr, const h4v* __restrict__ cs4,
        int M, int N, int K) {
    __shared__ _Float16 sA[128][72];
    __shared__ _Float16 sB[128][72];
    const int t = threadIdx.x;
    const int w = t >> 6, lane = t & 63, lq = lane & 31, hi = lane >> 5;
    const int wr = w >> 1, wc = w & 1;
    // XCD-chunked block remap: consecutive new ids share A row-panel + same XCD
    const int nwg = gridDim.x * gridDim.y;
    const int bidr = xcd_swz(blockIdx.y * gridDim.x + blockIdx.x, nwg);
    const int bx = bidr % gridDim.x, by = bidr / gridDim.x;
    const int m0 = by * 128, n0 = bx * 128;
    const int sw = ((lq >> 3) & 3) << 3;

    f32x16 acc[2][2];
#pragma unroll
    for (int m = 0; m < 2; ++m)
#pragma unroll
        for (int n = 0; n < 2; ++n) acc[m][n] = (f32x16)0.0f;

    const int sr = t >> 1, skc = (t & 1) * 16;
    const int swr = ((sr >> 3) & 3) << 3;
    const _Float16* Ap = A + (size_t)(m0 + sr) * K + skc;
    const _Float16* Bp = B + (size_t)(n0 + sr) * K + skc;

    for (int k0 = 0; k0 < K; k0 += 32) {
        us8 a0 = *reinterpret_cast<const us8*>(Ap + k0);
        us8 a1 = *reinterpret_cast<const us8*>(Ap + k0 + 8);
        us8 b0 = *reinterpret_cast<const us8*>(Bp + k0);
        us8 b1 = *reinterpret_cast<const us8*>(Bp + k0 + 8);
        __syncthreads();
        *reinterpret_cast<us8*>(&sA[sr][(skc) ^ swr])     = a0;
        *reinterpret_cast<us8*>(&sA[sr][(skc + 8) ^ swr]) = a1;
        *reinterpret_cast<us8*>(&sB[sr][(skc) ^ swr])     = b0;
        *reinterpret_cast<us8*>(&sB[sr][(skc + 8) ^ swr]) = b1;
        __syncthreads();
        hfrag fa[2][2], fb[2][2];
#pragma unroll
        for (int mb = 0; mb < 2; ++mb)
#pragma unroll
            for (int kc = 0; kc < 2; ++kc)
                fa[mb][kc] = *reinterpret_cast<const hfrag*>(
                    &sA[wr * 64 + mb * 32 + lq][(kc * 16 + 8 * hi) ^ sw]);
#pragma unroll
        for (int nb = 0; nb < 2; ++nb)
#pragma unroll
            for (int kc = 0; kc < 2; ++kc)
                fb[nb][kc] = *reinterpret_cast<const hfrag*>(
                    &sB[wc * 64 + nb * 32 + lq][(kc * 16 + 8 * hi) ^ sw]);
#pragma unroll
        for (int kc = 0; kc < 2; ++kc)
#pragma unroll
            for (int mb = 0; mb < 2; ++mb)
#pragma unroll
                for (int nb = 0; nb < 2; ++nb)
                    acc[mb][nb] = MFMA32H(fa[mb][kc], fb[nb][kc], acc[mb][nb]);
    }
    if (EPI == 4) {
        const int b64 = bx * 2 + wc;   // 64-col block index in [0,48)
        const int qk = b64 % 3, hh = b64 / 3;
        const float bv0 = bias[n0 + wc * 64 + lq];
        const float bv1 = bias[n0 + wc * 64 + 32 + lq];
#pragma unroll
        for (int mb = 0; mb < 2; ++mb)
#pragma unroll
            for (int g = 0; g < 4; ++g)
#pragma unroll
                for (int rr = 0; rr < 4; ++rr) {
                    int r = 4 * g + rr;
                    int rowg = m0 + wr * 64 + mb * 32 + rr + 8 * g + 4 * hi;
                    int s = rowg & (NS - 1), bb = rowg >> 11;
                    float v0 = acc[mb][0][r] + bv0;
                    float v1 = acc[mb][1][r] + bv1;
                    _Float16* dstb = (qk == 0 ? Qp : (qk == 1 ? Kp : Vr))
                        + ((size_t)(bb * HH + hh) * NS + s) * HDD;
                    if (qk < 2) {
                        h4v cs = cs4[(size_t)s * 32 + lq];
                        float c1 = (float)cs[0], s1 = (float)cs[1];
                        float c2 = (float)cs[2], s2 = (float)cs[3];
                        dstb[lq]      = (_Float16)(v0 * c1 - v1 * s1);
                        dstb[32 + lq] = (_Float16)(v1 * c2 + v0 * s2);
                    } else {
                        dstb[lq]      = (_Float16)v0;
                        dstb[32 + lq] = (_Float16)v1;
                    }
                }
        return;
    }
#pragma unroll
    for (int mb = 0; mb < 2; ++mb)
#pragma unroll
        for (int nb = 0; nb < 2; ++nb) {
            int colg = n0 + wc * 64 + nb * 32 + lq;
            float bv = bias[colg];
#pragma unroll
            for (int r = 0; r < 16; ++r) {
                int rowg = m0 + wr * 64 + mb * 32 + (r & 3) + 8 * (r >> 2) + 4 * hi;
                float v = acc[mb][nb][r] + bv;
                if (EPI == 1) v += resid[(size_t)rowg * N + colg];
                if (EPI == 2) {
                    Ch[(size_t)rowg * N + colg] = (_Float16)gelu_f(v);
                } else {
                    Cf[(size_t)rowg * N + colg] = v;
                }
            }
        }
}

// ---------------- fp16 MFMA GEMM, 64x128 tile, XCD-chunked grid
__global__ __launch_bounds__(256, 2) void gemm_h2(
        const _Float16* __restrict__ A, const _Float16* __restrict__ B,
        const float* __restrict__ bias, const float* __restrict__ resid,
        float* __restrict__ Cf, int M, int N, int K) {
    __shared__ _Float16 sA[64][72];
    __shared__ _Float16 sB[128][72];
    const int t = threadIdx.x;
    const int w = t >> 6, lane = t & 63, lq = lane & 31, hi = lane >> 5;
    const int nwg = gridDim.x * gridDim.y;
    const int bidr = xcd_swz(blockIdx.y * gridDim.x + blockIdx.x, nwg);
    const int bx = bidr % gridDim.x, by = bidr / gridDim.x;
    const int m0 = by * 64, n0 = bx * 128;
    const int sw = ((lq >> 3) & 3) << 3;

    f32x16 acc[2];
    acc[0] = (f32x16)0.0f; acc[1] = (f32x16)0.0f;

    const int ar = t >> 2, akc = (t & 3) * 8;
    const int aswr = ((ar >> 3) & 3) << 3;
    const int br = t >> 1, bkc = (t & 1) * 16;
    const int bswr = ((br >> 3) & 3) << 3;
    const _Float16* Ap = A + (size_t)(m0 + ar) * K + akc;
    const _Float16* Bp = B + (size_t)(n0 + br) * K + bkc;

    for (int k0 = 0; k0 < K; k0 += 32) {
        us8 a0 = *reinterpret_cast<const us8*>(Ap + k0);
        us8 b0 = *reinterpret_cast<const us8*>(Bp + k0);
        us8 b1 = *reinterpret_cast<const us8*>(Bp + k0 + 8);
        __syncthreads();
        *reinterpret_cast<us8*>(&sA[ar][(akc) ^ aswr])     = a0;
        *reinterpret_cast<us8*>(&sB[br][(bkc) ^ bswr])     = b0;
        *reinterpret_cast<us8*>(&sB[br][(bkc + 8) ^ bswr]) = b1;
        __syncthreads();
        hfrag fa[2][2], fb[2];
#pragma unroll
        for (int mb = 0; mb < 2; ++mb)
#pragma unroll
            for (int kc = 0; kc < 2; ++kc)
                fa[mb][kc] = *reinterpret_cast<const hfrag*>(
                    &sA[mb * 32 + lq][(kc * 16 + 8 * hi) ^ sw]);
#pragma unroll
        for (int kc = 0; kc < 2; ++kc)
            fb[kc] = *reinterpret_cast<const hfrag*>(
                &sB[32 * w + lq][(kc * 16 + 8 * hi) ^ sw]);
#pragma unroll
        for (int kc = 0; kc < 2; ++kc)
#pragma unroll
            for (int mb = 0; mb < 2; ++mb)
                acc[mb] = MFMA32H(fa[mb][kc], fb[kc], acc[mb]);
    }
    int colg = n0 + 32 * w + lq;
    float bv = bias[colg];
#pragma unroll
    for (int mb = 0; mb < 2; ++mb)
#pragma unroll
        for (int r = 0; r < 16; ++r) {
            int rowg = m0 + mb * 32 + (r & 3) + 8 * (r >> 2) + 4 * hi;
            float v = acc[mb][r] + bv + resid[(size_t)rowg * N + colg];
            Cf[(size_t)rowg * N + colg] = v;
        }
}

extern "C" void kernel_launch(void* const* d_in, const int* in_sizes, int n_in,
                              void* d_out, int out_size, void* d_ws, size_t ws_size,
                              hipStream_t stream) {
    const float* x        = (const float*)d_in[0];
    const int*   mask     = (const int*)d_in[1];
    const float* pos_bias = (const float*)d_in[2];
    const float* sp       = (const float*)d_in[3];
    const float* Wqkv     = (const float*)d_in[4];
    const float* bqkv     = (const float*)d_in[5];
    const float* Wo       = (const float*)d_in[6];
    const float* bo       = (const float*)d_in[7];
    const float* W1       = (const float*)d_in[8];
    const float* b1       = (const float*)d_in[9];
    const float* W2       = (const float*)d_in[10];
    const float* b2       = (const float*)d_in[11];
    const float* g1       = (const float*)d_in[12];
    const float* be1      = (const float*)d_in[13];
    const float* g2       = (const float*)d_in[14];
    const float* be2      = (const float*)d_in[15];
    float* out = (float*)d_out;
    char* wsb = (char*)d_ws;

    // ws layout (131 MB):
    //  [0,16M) xbuf ; [16,24M) actF fp16 ; [24,32M) wT fp16
    //  [32,33M) cs4 ; [34,38M) mask bytes
    //  [48,56M) Vr ; [72,80M) Qp ; [80,88M) Kp ; [88,96M) Vt
    //  hF fp16 overlaps [48,80M) after attn
    //  [96,128M) Opart f32 ; [130,131M) Lpart
    float*          xbuf  = (float*)(wsb);
    _Float16*       actF  = (_Float16*)(wsb + ((size_t)16 << 20));
    _Float16*       wT    = (_Float16*)(wsb + ((size_t)24 << 20));
    h4v*            cs4   = (h4v*)(wsb + ((size_t)32 << 20));
    unsigned char*  mkb   = (unsigned char*)(wsb + ((size_t)34 << 20));
    _Float16*       Vr    = (_Float16*)(wsb + ((size_t)48 << 20));
    _Float16*       Qp    = (_Float16*)(wsb + ((size_t)72 << 20));
    _Float16*       Kp    = (_Float16*)(wsb + ((size_t)80 << 20));
    _Float16*       Vt    = (_Float16*)(wsb + ((size_t)88 << 20));
    _Float16*       hF    = (_Float16*)(wsb + ((size_t)48 << 20));
    float*          Opart = (float*)(wsb + ((size_t)96 << 20));
    float2*         Lpart = (float2*)(wsb + ((size_t)130 << 20));

    // 1. xn = LN1(x) ; cos/sin table ; mask bytes
    ln_kernel<<<NR, 256, 0, stream>>>(x, g1, be1, xbuf, actF);
    cs4_table<<<(NS * 32) / 256, 256, 0, stream>>>(sp, cs4);
    mask8<<<(NS * NS / 4) / 256, 256, 0, stream>>>(mask, mkb);
    // 2. qkv GEMM with fused RoPE epilogue -> Qp/Kp (rope'd) + Vr
    wt_convert<<<dim3(TDQ / 32, DD / 32), 256, 0, stream>>>(Wqkv, wT, DD, TDQ);
    gemm_h<4><<<dim3(TDQ / 128, NR / 128), 256, 0, stream>>>(
        actF, wT, bqkv, nullptr, nullptr, nullptr, Qp, Kp, Vr, cs4, NR, TDQ, DD);
    // 3. V transpose
    vtrans<<<dim3(NS / 64, NB * HH), 256, 0, stream>>>(Vr, Vt);
    // 4. attention: batch-paired blocks, split-KV x2 + combine -> actF
    attn_mfma<<<dim3(NS / 128, HH, NSP), 256, 0, stream>>>(
        Qp, Kp, Vt, pos_bias, mkb, Opart, Lpart);
    attn_combine<<<dim3(NS / 128, NB * HH), 256, 0, stream>>>(Opart, Lpart, actF);
    // 5. x1 = xn + vals @ Wo + bo
    wt_convert<<<dim3(DD / 32, DD / 32), 256, 0, stream>>>(Wo, wT, DD, DD);
    gemm_h2<<<dim3(DD / 128, NR / 64), 256, 0, stream>>>(
        actF, wT, bo, xbuf, xbuf, NR, DD, DD);
    // 6. x2 = LN2(x1)
    ln_kernel<<<NR, 256, 0, stream>>>(xbuf, g2, be2, xbuf, actF);
    // 7. h = gelu(x2 @ W1 + b1) (fp16)
    wt_convert<<<dim3(FFF / 32, DD / 32), 256, 0, stream>>>(W1, wT, DD, FFF);
    gemm_h<2><<<dim3(FFF / 128, NR / 128), 256, 0, stream>>>(
        actF, wT, b1, nullptr, nullptr, hF, nullptr, nullptr, nullptr, nullptr,
        NR, FFF, DD);
    // 8. out = x2 + h @ W2 + b2
    wt_convert<<<dim3(DD / 32, FFF / 32), 256, 0, stream>>>(W2, wT, FFF, DD);
    gemm_h2<<<dim3(DD / 128, NR / 64), 256, 0, stream>>>(
        hF, wT, b2, xbuf, out, NR, DD, FFF);
}

// Round 17
// 404.131 us; speedup vs baseline: 1.0181x; 1.0181x over previous
//
#include <hip/hip_runtime.h>
#include <math.h>

// Problem constants (B=2, S=2048, D=1024, H=16, HD=64, FF=4096)
#define DD   1024
#define HH   16
#define HDD  64
#define FFF  4096
#define NB   2
#define NS   2048
#define NR   (NB * NS)     // 4096 rows
#define TDQ  (3 * DD)      // 3072
#define NKT  (NS / 64)     // 32 KV tiles
#define NSP  2             // KV splits

typedef __attribute__((ext_vector_type(8))) _Float16 hfrag;      // 8 fp16 (MFMA A/B operand)
typedef __attribute__((ext_vector_type(4))) _Float16 h4v;        // 8B pack
typedef __attribute__((ext_vector_type(16))) float f32x16;       // MFMA 32x32 C/D
typedef __attribute__((ext_vector_type(8))) unsigned short us8;  // 16B chunk
typedef __attribute__((ext_vector_type(4))) unsigned int u32x4;

__device__ __forceinline__ float4 ld4(const float* p) {
    return *reinterpret_cast<const float4*>(p);
}
__device__ __forceinline__ float gelu_f(float x) {
    return 0.5f * x * (1.0f + erff(x * 0.70710678118654752440f));
}
#define MFMA32H(a, b, c) __builtin_amdgcn_mfma_f32_32x32x16_f16((a), (b), (c), 0, 0, 0)

// ---------------- LayerNorm: fp32 out + fp16 plane
__global__ __launch_bounds__(256) void ln_kernel(const float* __restrict__ in,
        const float* __restrict__ gw, const float* __restrict__ bw,
        float* __restrict__ outf, _Float16* __restrict__ oh) {
    int row = blockIdx.x;
    float4 v = reinterpret_cast<const float4*>(in + (size_t)row * DD)[threadIdx.x];
    float s1 = v.x + v.y + v.z + v.w;
    float s2 = v.x * v.x + v.y * v.y + v.z * v.z + v.w * v.w;
#pragma unroll
    for (int off = 1; off < 64; off <<= 1) {
        s1 += __shfl_xor(s1, off);
        s2 += __shfl_xor(s2, off);
    }
    __shared__ float r1[4], r2[4];
    int wid = threadIdx.x >> 6;
    if ((threadIdx.x & 63) == 0) { r1[wid] = s1; r2[wid] = s2; }
    __syncthreads();
    s1 = r1[0] + r1[1] + r1[2] + r1[3];
    s2 = r2[0] + r2[1] + r2[2] + r2[3];
    float mu   = s1 * (1.0f / DD);
    float var  = s2 * (1.0f / DD) - mu * mu;
    float rstd = rsqrtf(var + 1e-5f);
    float4 g = reinterpret_cast<const float4*>(gw)[threadIdx.x];
    float4 b = reinterpret_cast<const float4*>(bw)[threadIdx.x];
    float o[4];
    o[0] = (v.x - mu) * rstd * g.x + b.x;
    o[1] = (v.y - mu) * rstd * g.y + b.y;
    o[2] = (v.z - mu) * rstd * g.z + b.z;
    o[3] = (v.w - mu) * rstd * g.w + b.w;
    float4 of; of.x = o[0]; of.y = o[1]; of.z = o[2]; of.w = o[3];
    reinterpret_cast<float4*>(outf + (size_t)row * DD)[threadIdx.x] = of;
    h4v hv;
#pragma unroll
    for (int j = 0; j < 4; ++j) hv[j] = (_Float16)o[j];
    *reinterpret_cast<h4v*>(oh + (size_t)row * DD + threadIdx.x * 4) = hv;
}

// ---------------- Weight transpose: W[K][N] fp32 -> T[N][K] fp16
__global__ __launch_bounds__(256) void wt_convert(const float* __restrict__ W,
        _Float16* __restrict__ Th, int K, int N) {
    __shared__ float s[32][33];
    int tx = threadIdx.x & 31, ty = threadIdx.x >> 5;
    int n0 = blockIdx.x * 32, k0 = blockIdx.y * 32;
#pragma unroll
    for (int i = 0; i < 4; ++i)
        s[ty + i * 8][tx] = W[(size_t)(k0 + ty + i * 8) * N + n0 + tx];
    __syncthreads();
#pragma unroll
    for (int i = 0; i < 4; ++i) {
        int n = n0 + ty + i * 8;
        Th[(size_t)n * K + k0 + tx] = (_Float16)s[tx][ty + i * 8];
    }
}

// ---------------- packed cos/sin table
__global__ __launch_bounds__(256) void cs4_table(const float* __restrict__ sp,
        h4v* __restrict__ cs4) {
    int i = blockIdx.x * 256 + threadIdx.x;   // NS*32 total
    int s = i >> 5, d = i & 31;
    float a = sp[s * 64 + d], b = sp[s * 64 + d + 32];
    h4v v;
    v[0] = (_Float16)cosf(a); v[1] = (_Float16)sinf(a);
    v[2] = (_Float16)cosf(b); v[3] = (_Float16)sinf(b);
    cs4[i] = v;
}

// ---------------- mask int32 -> byte
__global__ __launch_bounds__(256) void mask8(const int* __restrict__ mask,
        unsigned char* __restrict__ mb) {
    int i = blockIdx.x * 256 + threadIdx.x;
    int4 v = reinterpret_cast<const int4*>(mask)[i];
    unsigned int o = (unsigned int)(v.x & 1) | ((unsigned int)(v.y & 1) << 8)
                   | ((unsigned int)(v.z & 1) << 16) | ((unsigned int)(v.w & 1) << 24);
    reinterpret_cast<unsigned int*>(mb)[i] = o;
}

// ---------------- V-only transpose: Vr [bh][s][64] -> Vt [bh][d][NS]
__global__ __launch_bounds__(256) void vtrans(const _Float16* __restrict__ Vr,
        _Float16* __restrict__ Vt) {
    __shared__ _Float16 sv[64][72];
    const int t = threadIdx.x;
    const int tile = blockIdx.x, bh = blockIdx.y;
    const int r = t >> 2, p = t & 3;
    const _Float16* src = Vr + ((size_t)bh * NS + tile * 64 + r) * HDD;
    hfrag v0 = *reinterpret_cast<const hfrag*>(src + p * 16);
    hfrag v1 = *reinterpret_cast<const hfrag*>(src + p * 16 + 8);
#pragma unroll
    for (int j = 0; j < 8; ++j) {
        sv[p * 16 + j][r]     = v0[j];
        sv[p * 16 + 8 + j][r] = v1[j];
    }
    __syncthreads();
    {
        int d = t >> 2, kb = (t & 3) * 16;
        size_t obase = ((size_t)bh * HDD + d) * NS + tile * 64 + kb;
        *reinterpret_cast<hfrag*>(Vt + obase)     = *reinterpret_cast<hfrag*>(&sv[d][kb]);
        *reinterpret_cast<hfrag*>(Vt + obase + 8) = *reinterpret_cast<hfrag*>(&sv[d][kb + 8]);
    }
}

// ---------------- Flash attention, batch-paired with forced chain overlap:
// phase 1 computes QK for BOTH batches (MFMA pipe stays busy through sm0),
// phase 2 does softmax+PV per batch. Split-KV x2, fp32 partials.
__global__ __launch_bounds__(256) void attn_mfma(
        const _Float16* __restrict__ Qp, const _Float16* __restrict__ Kp,
        const _Float16* __restrict__ Vt,
        const float* __restrict__ pos_bias, const unsigned char* __restrict__ maskb,
        float* __restrict__ Opart, float2* __restrict__ Lpart) {
    __shared__ _Float16 kT[2][64][72];    // [batch][kv][d], swizzled
    __shared__ _Float16 vT[2][64][72];    // [batch][d][kv], swizzled
    __shared__ _Float16 PBs[4][32][68];   // per-wave masked bias (shared by batches)
    const int t = threadIdx.x;
    const int w = t >> 6, lane = t & 63, lq = lane & 31, hi = lane >> 5;
    const int h = blockIdx.y;
    const int qt = blockIdx.x, sp = blockIdx.z;
    const int q0 = qt * 128;
    const int qg = q0 + 32 * w + lq;
    const int sw = ((lq >> 3) & 3) << 3;
    const int KT0 = sp * (NKT / NSP), KT1 = KT0 + (NKT / NSP);
    const float C1  = 0.18033688011112042f;   // 0.125 * log2(e)
    const float THR = 11.5f;

    hfrag qf[2][4];
#pragma unroll
    for (int bt = 0; bt < 2; ++bt)
#pragma unroll
        for (int dk = 0; dk < 4; ++dk)
            qf[bt][dk] = *reinterpret_cast<const hfrag*>(
                Qp + ((size_t)(bt * HH + h) * NS + qg) * HDD + 16 * dk + 8 * hi);

    f32x16 o[2][2];
#pragma unroll
    for (int bt = 0; bt < 2; ++bt) { o[bt][0] = (f32x16)0.0f; o[bt][1] = (f32x16)0.0f; }
    float mrun[2] = { -INFINITY, -INFINITY }, lsum[2] = { 0.0f, 0.0f };

    const int sr0 = t >> 2, sc = t & 3;
    const int swr = ((sr0 >> 3) & 3) << 3;
    const int brow = lane >> 4;
    const int bcol = (lane & 15) * 4;
    us8 kr[2][2], vr[2][2];
    float4 pbr[8]; unsigned int pmk[8];

#define STAGE_LOAD(KT) {                                                        \
        int kv0_ = (KT) * 64;                                                   \
        _Pragma("unroll")                                                       \
        for (int bt = 0; bt < 2; ++bt) {                                        \
            size_t kb_ = ((size_t)(bt * HH + h) * NS + kv0_ + sr0) * HDD + 16 * sc; \
            size_t vb_ = ((size_t)(bt * HH + h) * HDD + sr0) * NS + kv0_ + 16 * sc; \
            kr[bt][0] = *reinterpret_cast<const us8*>(Kp + kb_);                \
            kr[bt][1] = *reinterpret_cast<const us8*>(Kp + kb_ + 8);            \
            vr[bt][0] = *reinterpret_cast<const us8*>(Vt + vb_);                \
            vr[bt][1] = *reinterpret_cast<const us8*>(Vt + vb_ + 8);            \
        }                                                                       \
        _Pragma("unroll")                                                       \
        for (int i = 0; i < 8; ++i) {                                           \
            int rg_ = q0 + 32 * w + brow + 4 * i;                               \
            pbr[i] = ld4(pos_bias + ((size_t)h * NS + rg_) * NS + kv0_ + bcol); \
            pmk[i] = *reinterpret_cast<const unsigned int*>(                    \
                         maskb + (size_t)rg_ * NS + kv0_ + bcol);               \
        }                                                                       \
    }

    STAGE_LOAD(KT0);
    for (int kt = KT0; kt < KT1; ++kt) {
        __syncthreads();
#pragma unroll
        for (int bt = 0; bt < 2; ++bt) {
            *reinterpret_cast<us8*>(&kT[bt][sr0][(16 * sc) ^ swr])     = kr[bt][0];
            *reinterpret_cast<us8*>(&kT[bt][sr0][(16 * sc + 8) ^ swr]) = kr[bt][1];
            *reinterpret_cast<us8*>(&vT[bt][sr0][(16 * sc) ^ swr])     = vr[bt][0];
            *reinterpret_cast<us8*>(&vT[bt][sr0][(16 * sc + 8) ^ swr]) = vr[bt][1];
        }
#pragma unroll
        for (int i = 0; i < 8; ++i) {
            h4v pv;
#pragma unroll
            for (int j = 0; j < 4; ++j)
                pv[j] = ((pmk[i] >> (8 * j)) & 0xffu)
                      ? (_Float16)(pbr[i][j] * C1) : (_Float16)(-60000.0f);
            *reinterpret_cast<h4v*>(&PBs[w][brow + 4 * i][bcol]) = pv;
        }
        __syncthreads();
        if (kt + 1 < KT1) STAGE_LOAD(kt + 1);

        // ---- phase 1: QK^T for BOTH batches (32 MFMAs back-to-back; keeps
        // the matrix pipe busy through phase-2's softmax dependency stalls)
        f32x16 sS[2][2];
#pragma unroll
        for (int bt = 0; bt < 2; ++bt) {
            sS[bt][0] = (f32x16)0.0f; sS[bt][1] = (f32x16)0.0f;
#pragma unroll
            for (int dk = 0; dk < 4; ++dk) {
                hfrag k0 = *reinterpret_cast<const hfrag*>(
                    &kT[bt][lq][(16 * dk + 8 * hi) ^ sw]);
                hfrag k1 = *reinterpret_cast<const hfrag*>(
                    &kT[bt][32 + lq][(16 * dk + 8 * hi) ^ sw]);
                sS[bt][0] = MFMA32H(k0, qf[bt][dk], sS[bt][0]);
                sS[bt][1] = MFMA32H(k1, qf[bt][dk], sS[bt][1]);
            }
        }
        // ---- phase 2: softmax + PV per batch
#pragma unroll
        for (int bt = 0; bt < 2; ++bt) {
            float sv[2][16];
#pragma unroll
            for (int m2 = 0; m2 < 2; ++m2)
#pragma unroll
                for (int g = 0; g < 4; ++g) {
                    h4v pb4 = *reinterpret_cast<const h4v*>(
                        &PBs[w][lq][32 * m2 + 8 * g + 4 * hi]);
#pragma unroll
                    for (int j = 0; j < 4; ++j) {
                        int r = 4 * g + j;
                        sv[m2][r] = fmaf(sS[bt][m2][r], C1, (float)pb4[j]);
                    }
                }
            float mx = sv[0][0];
#pragma unroll
            for (int m2 = 0; m2 < 2; ++m2)
#pragma unroll
                for (int r = 0; r < 16; ++r) mx = fmaxf(mx, sv[m2][r]);
            mx = fmaxf(mx, __shfl_xor(mx, 32));
            if (__any(mx > mrun[bt] + THR)) {
                float mnew = fmaxf(mrun[bt], mx);
                float corr = __builtin_amdgcn_exp2f(mrun[bt] - mnew);
                lsum[bt] *= corr;
                mrun[bt] = mnew;
#pragma unroll
                for (int r = 0; r < 16; ++r) {
                    int iq = (r & 3) + 8 * (r >> 2) + 4 * hi;
                    float cr = __shfl(corr, iq);
                    o[bt][0][r] *= cr; o[bt][1][r] *= cr;
                }
            }
            float ps = 0.0f;
            hfrag af[4];
#pragma unroll
            for (int m2 = 0; m2 < 2; ++m2)
#pragma unroll
                for (int gp = 0; gp < 2; ++gp) {
                    float p0 = __builtin_amdgcn_exp2f(sv[m2][8 * gp + 0] - mrun[bt]);
                    float p1 = __builtin_amdgcn_exp2f(sv[m2][8 * gp + 1] - mrun[bt]);
                    float p2 = __builtin_amdgcn_exp2f(sv[m2][8 * gp + 2] - mrun[bt]);
                    float p3 = __builtin_amdgcn_exp2f(sv[m2][8 * gp + 3] - mrun[bt]);
                    float p4 = __builtin_amdgcn_exp2f(sv[m2][8 * gp + 4] - mrun[bt]);
                    float p5 = __builtin_amdgcn_exp2f(sv[m2][8 * gp + 5] - mrun[bt]);
                    float p6 = __builtin_amdgcn_exp2f(sv[m2][8 * gp + 6] - mrun[bt]);
                    float p7 = __builtin_amdgcn_exp2f(sv[m2][8 * gp + 7] - mrun[bt]);
                    ps += (p0 + p1) + (p2 + p3) + (p4 + p5) + (p6 + p7);
                    unsigned int XA = __builtin_bit_cast(unsigned int, __builtin_amdgcn_cvt_pkrtz(p0, p1));
                    unsigned int XB = __builtin_bit_cast(unsigned int, __builtin_amdgcn_cvt_pkrtz(p2, p3));
                    unsigned int XC = __builtin_bit_cast(unsigned int, __builtin_amdgcn_cvt_pkrtz(p4, p5));
                    unsigned int XD = __builtin_bit_cast(unsigned int, __builtin_amdgcn_cvt_pkrtz(p6, p7));
                    unsigned int YA = (unsigned int)__shfl_xor((int)XA, 32);
                    unsigned int YB = (unsigned int)__shfl_xor((int)XB, 32);
                    unsigned int YC = (unsigned int)__shfl_xor((int)XC, 32);
                    unsigned int YD = (unsigned int)__shfl_xor((int)XD, 32);
                    u32x4 aw;
                    aw[0] = hi ? YC : XA;
                    aw[1] = hi ? YD : XB;
                    aw[2] = hi ? XC : YA;
                    aw[3] = hi ? XD : YB;
                    af[m2 * 2 + gp] = __builtin_bit_cast(hfrag, aw);
                }
            ps += __shfl_xor(ps, 32);
            lsum[bt] += ps;
#pragma unroll
            for (int kp = 0; kp < 4; ++kp) {
                hfrag v0 = *reinterpret_cast<const hfrag*>(
                    &vT[bt][lq][(16 * kp + 8 * hi) ^ sw]);
                hfrag v1 = *reinterpret_cast<const hfrag*>(
                    &vT[bt][32 + lq][(16 * kp + 8 * hi) ^ sw]);
                o[bt][0] = MFMA32H(af[kp], v0, o[bt][0]);
                o[bt][1] = MFMA32H(af[kp], v1, o[bt][1]);
            }
        }
    }
#undef STAGE_LOAD
#pragma unroll
    for (int bt = 0; bt < 2; ++bt) {
        size_t obase = (((size_t)((bt * HH + h) * 16 + qt)) * NSP + sp) * (size_t)(128 * 64);
#pragma unroll
        for (int r = 0; r < 16; ++r) {
            int iq = (r & 3) + 8 * (r >> 2) + 4 * hi;
            Opart[obase + (size_t)(32 * w + iq) * 64 + lq]      = o[bt][0][r];
            Opart[obase + (size_t)(32 * w + iq) * 64 + 32 + lq] = o[bt][1][r];
        }
        if (hi == 0) {
            float2 ml; ml.x = mrun[bt]; ml.y = lsum[bt];
            Lpart[(((size_t)((bt * HH + h) * 16 + qt)) * NSP + sp) * 128 + 32 * w + lq] = ml;
        }
    }
}

// ---------------- combine the two KV-split partials -> fp16 vals
__global__ __launch_bounds__(256) void attn_combine(const float* __restrict__ Opart,
        const float2* __restrict__ Lpart, _Float16* __restrict__ valf) {
    const int qt = blockIdx.x;
    const int h = blockIdx.y >> 1, b = blockIdx.y & 1;
    const int bh = b * HH + h;
    const int t = threadIdx.x;
    const int qloc = t >> 2, d0 = (t & 3) * 16;
    size_t base = ((size_t)(bh * 16 + qt)) * NSP;
#pragma unroll
    for (int half = 0; half < 2; ++half) {
        int q = qloc + 64 * half;
        float2 ml0 = Lpart[(base + 0) * 128 + q];
        float2 ml1 = Lpart[(base + 1) * 128 + q];
        float m = fmaxf(ml0.x, ml1.x);
        float a0 = __builtin_amdgcn_exp2f(ml0.x - m);
        float a1 = __builtin_amdgcn_exp2f(ml1.x - m);
        float inv = 1.0f / (ml0.y * a0 + ml1.y * a1);
        const float* O0 = Opart + (base + 0) * 8192 + (size_t)q * 64 + d0;
        const float* O1 = Opart + (base + 1) * 8192 + (size_t)q * 64 + d0;
        _Float16* dst = valf + ((size_t)(b * NS + qt * 128 + q)) * DD + h * HDD + d0;
#pragma unroll
        for (int j = 0; j < 4; ++j) {
            float4 x0 = ld4(O0 + 4 * j), x1 = ld4(O1 + 4 * j);
            h4v o;
            o[0] = (_Float16)((x0.x * a0 + x1.x * a1) * inv);
            o[1] = (_Float16)((x0.y * a0 + x1.y * a1) * inv);
            o[2] = (_Float16)((x0.z * a0 + x1.z * a1) * inv);
            o[3] = (_Float16)((x0.w * a0 + x1.w * a1) * inv);
            *reinterpret_cast<h4v*>(dst + 4 * j) = o;
        }
    }
}

// ---------------- fp16 MFMA GEMM, 128x128 tile, swizzled LDS.
// EPI: 1 +bias+resid fp32 ; 2 gelu(+bias) fp16 ; 4 QKV fused-RoPE epilogue.
template<int EPI>
__global__ __launch_bounds__(256, 2) void gemm_h(
        const _Float16* __restrict__ A, const _Float16* __restrict__ B,
        const float* __restrict__ bias, const float* __restrict__ resid,
        float* __restrict__ Cf, _Float16* __restrict__ Ch,
        _Float16* __restrict__ Qp, _Float16* __restrict__ Kp,
        _Float16* __restrict__ Vr, const h4v* __restrict__ cs4,
        int M, int N, int K) {
    __shared__ _Float16 sA[128][72];
    __shared__ _Float16 sB[128][72];
    const int t = threadIdx.x;
    const int w = t >> 6, lane = t & 63, lq = lane & 31, hi = lane >> 5;
    const int wr = w >> 1, wc = w & 1;
    const int m0 = blockIdx.y * 128, n0 = blockIdx.x * 128;
    const int sw = ((lq >> 3) & 3) << 3;

    f32x16 acc[2][2];
#pragma unroll
    for (int m = 0; m < 2; ++m)
#pragma unroll
        for (int n = 0; n < 2; ++n) acc[m][n] = (f32x16)0.0f;

    const int sr = t >> 1, skc = (t & 1) * 16;
    const int swr = ((sr >> 3) & 3) << 3;
    const _Float16* Ap = A + (size_t)(m0 + sr) * K + skc;
    const _Float16* Bp = B + (size_t)(n0 + sr) * K + skc;

    for (int k0 = 0; k0 < K; k0 += 32) {
        us8 a0 = *reinterpret_cast<const us8*>(Ap + k0);
        us8 a1 = *reinterpret_cast<const us8*>(Ap + k0 + 8);
        us8 b0 = *reinterpret_cast<const us8*>(Bp + k0);
        us8 b1 = *reinterpret_cast<const us8*>(Bp + k0 + 8);
        __syncthreads();
        *reinterpret_cast<us8*>(&sA[sr][(skc) ^ swr])     = a0;
        *reinterpret_cast<us8*>(&sA[sr][(skc + 8) ^ swr]) = a1;
        *reinterpret_cast<us8*>(&sB[sr][(skc) ^ swr])     = b0;
        *reinterpret_cast<us8*>(&sB[sr][(skc + 8) ^ swr]) = b1;
        __syncthreads();
        hfrag fa[2][2], fb[2][2];
#pragma unroll
        for (int mb = 0; mb < 2; ++mb)
#pragma unroll
            for (int kc = 0; kc < 2; ++kc)
                fa[mb][kc] = *reinterpret_cast<const hfrag*>(
                    &sA[wr * 64 + mb * 32 + lq][(kc * 16 + 8 * hi) ^ sw]);
#pragma unroll
        for (int nb = 0; nb < 2; ++nb)
#pragma unroll
            for (int kc = 0; kc < 2; ++kc)
                fb[nb][kc] = *reinterpret_cast<const hfrag*>(
                    &sB[wc * 64 + nb * 32 + lq][(kc * 16 + 8 * hi) ^ sw]);
#pragma unroll
        for (int kc = 0; kc < 2; ++kc)
#pragma unroll
            for (int mb = 0; mb < 2; ++mb)
#pragma unroll
                for (int nb = 0; nb < 2; ++nb)
                    acc[mb][nb] = MFMA32H(fa[mb][kc], fb[nb][kc], acc[mb][nb]);
    }
    if (EPI == 4) {
        const int b64 = blockIdx.x * 2 + wc;   // 64-col block index in [0,48)
        const int qk = b64 % 3, hh = b64 / 3;
        const float bv0 = bias[n0 + wc * 64 + lq];
        const float bv1 = bias[n0 + wc * 64 + 32 + lq];
#pragma unroll
        for (int mb = 0; mb < 2; ++mb)
#pragma unroll
            for (int g = 0; g < 4; ++g)
#pragma unroll
                for (int rr = 0; rr < 4; ++rr) {
                    int r = 4 * g + rr;
                    int rowg = m0 + wr * 64 + mb * 32 + rr + 8 * g + 4 * hi;
                    int s = rowg & (NS - 1), bb = rowg >> 11;
                    float v0 = acc[mb][0][r] + bv0;
                    float v1 = acc[mb][1][r] + bv1;
                    _Float16* dstb = (qk == 0 ? Qp : (qk == 1 ? Kp : Vr))
                        + ((size_t)(bb * HH + hh) * NS + s) * HDD;
                    if (qk < 2) {
                        h4v cs = cs4[(size_t)s * 32 + lq];
                        float c1 = (float)cs[0], s1 = (float)cs[1];
                        float c2 = (float)cs[2], s2 = (float)cs[3];
                        dstb[lq]      = (_Float16)(v0 * c1 - v1 * s1);
                        dstb[32 + lq] = (_Float16)(v1 * c2 + v0 * s2);
                    } else {
                        dstb[lq]      = (_Float16)v0;
                        dstb[32 + lq] = (_Float16)v1;
                    }
                }
        return;
    }
#pragma unroll
    for (int mb = 0; mb < 2; ++mb)
#pragma unroll
        for (int nb = 0; nb < 2; ++nb) {
            int colg = n0 + wc * 64 + nb * 32 + lq;
            float bv = bias[colg];
#pragma unroll
            for (int r = 0; r < 16; ++r) {
                int rowg = m0 + wr * 64 + mb * 32 + (r & 3) + 8 * (r >> 2) + 4 * hi;
                float v = acc[mb][nb][r] + bv;
                if (EPI == 1) v += resid[(size_t)rowg * N + colg];
                if (EPI == 2) {
                    Ch[(size_t)rowg * N + colg] = (_Float16)gelu_f(v);
                } else {
                    Cf[(size_t)rowg * N + colg] = v;
                }
            }
        }
}

// ---------------- fp16 MFMA GEMM, 64x128 tile
__global__ __launch_bounds__(256, 2) void gemm_h2(
        const _Float16* __restrict__ A, const _Float16* __restrict__ B,
        const float* __restrict__ bias, const float* __restrict__ resid,
        float* __restrict__ Cf, int M, int N, int K) {
    __shared__ _Float16 sA[64][72];
    __shared__ _Float16 sB[128][72];
    const int t = threadIdx.x;
    const int w = t >> 6, lane = t & 63, lq = lane & 31, hi = lane >> 5;
    const int m0 = blockIdx.y * 64, n0 = blockIdx.x * 128;
    const int sw = ((lq >> 3) & 3) << 3;

    f32x16 acc[2];
    acc[0] = (f32x16)0.0f; acc[1] = (f32x16)0.0f;

    const int ar = t >> 2, akc = (t & 3) * 8;
    const int aswr = ((ar >> 3) & 3) << 3;
    const int br = t >> 1, bkc = (t & 1) * 16;
    const int bswr = ((br >> 3) & 3) << 3;
    const _Float16* Ap = A + (size_t)(m0 + ar) * K + akc;
    const _Float16* Bp = B + (size_t)(n0 + br) * K + bkc;

    for (int k0 = 0; k0 < K; k0 += 32) {
        us8 a0 = *reinterpret_cast<const us8*>(Ap + k0);
        us8 b0 = *reinterpret_cast<const us8*>(Bp + k0);
        us8 b1 = *reinterpret_cast<const us8*>(Bp + k0 + 8);
        __syncthreads();
        *reinterpret_cast<us8*>(&sA[ar][(akc) ^ aswr])     = a0;
        *reinterpret_cast<us8*>(&sB[br][(bkc) ^ bswr])     = b0;
        *reinterpret_cast<us8*>(&sB[br][(bkc + 8) ^ bswr]) = b1;
        __syncthreads();
        hfrag fa[2][2], fb[2];
#pragma unroll
        for (int mb = 0; mb < 2; ++mb)
#pragma unroll
            for (int kc = 0; kc < 2; ++kc)
                fa[mb][kc] = *reinterpret_cast<const hfrag*>(
                    &sA[mb * 32 + lq][(kc * 16 + 8 * hi) ^ sw]);
#pragma unroll
        for (int kc = 0; kc < 2; ++kc)
            fb[kc] = *reinterpret_cast<const hfrag*>(
                &sB[32 * w + lq][(kc * 16 + 8 * hi) ^ sw]);
#pragma unroll
        for (int kc = 0; kc < 2; ++kc)
#pragma unroll
            for (int mb = 0; mb < 2; ++mb)
                acc[mb] = MFMA32H(fa[mb][kc], fb[kc], acc[mb]);
    }
    int colg = n0 + 32 * w + lq;
    float bv = bias[colg];
#pragma unroll
    for (int mb = 0; mb < 2; ++mb)
#pragma unroll
        for (int r = 0; r < 16; ++r) {
            int rowg = m0 + mb * 32 + (r & 3) + 8 * (r >> 2) + 4 * hi;
            float v = acc[mb][r] + bv + resid[(size_t)rowg * N + colg];
            Cf[(size_t)rowg * N + colg] = v;
        }
}

extern "C" void kernel_launch(void* const* d_in, const int* in_sizes, int n_in,
                              void* d_out, int out_size, void* d_ws, size_t ws_size,
                              hipStream_t stream) {
    const float* x        = (const float*)d_in[0];
    const int*   mask     = (const int*)d_in[1];
    const float* pos_bias = (const float*)d_in[2];
    const float* sp       = (const float*)d_in[3];
    const float* Wqkv     = (const float*)d_in[4];
    const float* bqkv     = (const float*)d_in[5];
    const float* Wo       = (const float*)d_in[6];
    const float* bo       = (const float*)d_in[7];
    const float* W1       = (const float*)d_in[8];
    const float* b1       = (const float*)d_in[9];
    const float* W2       = (const float*)d_in[10];
    const float* b2       = (const float*)d_in[11];
    const float* g1       = (const float*)d_in[12];
    const float* be1      = (const float*)d_in[13];
    const float* g2       = (const float*)d_in[14];
    const float* be2      = (const float*)d_in[15];
    float* out = (float*)d_out;
    char* wsb = (char*)d_ws;

    // ws layout (131 MB)
    float*          xbuf  = (float*)(wsb);
    _Float16*       actF  = (_Float16*)(wsb + ((size_t)16 << 20));
    _Float16*       wT    = (_Float16*)(wsb + ((size_t)24 << 20));
    h4v*            cs4   = (h4v*)(wsb + ((size_t)32 << 20));
    unsigned char*  mkb   = (unsigned char*)(wsb + ((size_t)34 << 20));
    _Float16*       Vr    = (_Float16*)(wsb + ((size_t)48 << 20));
    _Float16*       Qp    = (_Float16*)(wsb + ((size_t)72 << 20));
    _Float16*       Kp    = (_Float16*)(wsb + ((size_t)80 << 20));
    _Float16*       Vt    = (_Float16*)(wsb + ((size_t)88 << 20));
    _Float16*       hF    = (_Float16*)(wsb + ((size_t)48 << 20));
    float*          Opart = (float*)(wsb + ((size_t)96 << 20));
    float2*         Lpart = (float2*)(wsb + ((size_t)130 << 20));

    // 1. xn = LN1(x) ; cos/sin table ; mask bytes
    ln_kernel<<<NR, 256, 0, stream>>>(x, g1, be1, xbuf, actF);
    cs4_table<<<(NS * 32) / 256, 256, 0, stream>>>(sp, cs4);
    mask8<<<(NS * NS / 4) / 256, 256, 0, stream>>>(mask, mkb);
    // 2. qkv GEMM with fused RoPE epilogue -> Qp/Kp (rope'd) + Vr
    wt_convert<<<dim3(TDQ / 32, DD / 32), 256, 0, stream>>>(Wqkv, wT, DD, TDQ);
    gemm_h<4><<<dim3(TDQ / 128, NR / 128), 256, 0, stream>>>(
        actF, wT, bqkv, nullptr, nullptr, nullptr, Qp, Kp, Vr, cs4, NR, TDQ, DD);
    // 3. V transpose
    vtrans<<<dim3(NS / 64, NB * HH), 256, 0, stream>>>(Vr, Vt);
    // 4. attention: batch-paired blocks (QK both batches first), split-KV x2
    attn_mfma<<<dim3(NS / 128, HH, NSP), 256, 0, stream>>>(
        Qp, Kp, Vt, pos_bias, mkb, Opart, Lpart);
    attn_combine<<<dim3(NS / 128, NB * HH), 256, 0, stream>>>(Opart, Lpart, actF);
    // 5. x1 = xn + vals @ Wo + bo
    wt_convert<<<dim3(DD / 32, DD / 32), 256, 0, stream>>>(Wo, wT, DD, DD);
    gemm_h2<<<dim3(DD / 128, NR / 64), 256, 0, stream>>>(
        actF, wT, bo, xbuf, xbuf, NR, DD, DD);
    // 6. x2 = LN2(x1)
    ln_kernel<<<NR, 256, 0, stream>>>(xbuf, g2, be2, xbuf, actF);
    // 7. h = gelu(x2 @ W1 + b1) (fp16)
    wt_convert<<<dim3(FFF / 32, DD / 32), 256, 0, stream>>>(W1, wT, DD, FFF);
    gemm_h<2><<<dim3(FFF / 128, NR / 128), 256, 0, stream>>>(
        actF, wT, b1, nullptr, nullptr, hF, nullptr, nullptr, nullptr, nullptr,
        NR, FFF, DD);
    // 8. out = x2 + h @ W2 + b2
    wt_convert<<<dim3(DD / 32, FFF / 32), 256, 0, stream>>>(W2, wT, FFF, DD);
    gemm_h2<<<dim3(DD / 128, NR / 64), 256, 0, stream>>>(
        hF, wT, b2, xbuf, out, NR, DD, FFF);
}